// Round 1
// baseline (734.689 us; speedup 1.0000x reference)
//
#include <hip/hip_runtime.h>

typedef __bf16 bf16;
typedef bf16 bf16x8 __attribute__((ext_vector_type(8)));
typedef bf16 bf16x4 __attribute__((ext_vector_type(4)));
typedef float f32x4 __attribute__((ext_vector_type(4)));

#define MFMA16(a, b, c) __builtin_amdgcn_mfma_f32_16x16x32_bf16(a, b, c, 0, 0, 0)

// ---------------- x -> bf16 ----------------
__global__ __launch_bounds__(256) void k_cvt_x(const float* __restrict__ x, bf16* __restrict__ o) {
    int i = (blockIdx.x * 256 + threadIdx.x) * 8;
    const float4* p = (const float4*)(x + i);
    float4 a = p[0], b = p[1];
    bf16x8 v;
    v[0] = (bf16)a.x; v[1] = (bf16)a.y; v[2] = (bf16)a.z; v[3] = (bf16)a.w;
    v[4] = (bf16)b.x; v[5] = (bf16)b.y; v[6] = (bf16)b.z; v[7] = (bf16)b.w;
    *(bf16x8*)(o + i) = v;
}

// ---------------- W [K][N] fp32 -> WT [N][K] bf16 ----------------
__global__ __launch_bounds__(256) void k_wt(const float* __restrict__ W, bf16* __restrict__ WT) {
    __shared__ bf16 lt[64][72];
    int t = threadIdx.x;
    int n0 = blockIdx.x * 64, k0 = blockIdx.y * 64;
#pragma unroll
    for (int j = 0; j < 4; j++) {
        int idx = t + 256 * j;
        int r = idx >> 4;             // k row 0..63
        int c4 = (idx & 15) << 2;     // n col
        float4 v = *(const float4*)&W[(size_t)(k0 + r) * 2048 + n0 + c4];
        lt[r][c4] = (bf16)v.x; lt[r][c4 + 1] = (bf16)v.y;
        lt[r][c4 + 2] = (bf16)v.z; lt[r][c4 + 3] = (bf16)v.w;
    }
    __syncthreads();
#pragma unroll
    for (int j = 0; j < 4; j++) {
        int idx = t + 256 * j;
        int n = idx >> 4;
        int k4 = (idx & 15) << 2;
        bf16x4 o;
        o[0] = lt[k4][n]; o[1] = lt[k4 + 1][n]; o[2] = lt[k4 + 2][n]; o[3] = lt[k4 + 3][n];
        *(bf16x4*)&WT[(size_t)(n0 + n) * 2048 + k0 + k4] = o;
    }
}

// ---------------- GEMM: C[M=1024][N=2048] = A[M][K=2048](bf16) * Bt[N][K]^T + bias, fp32 out ----
__global__ __launch_bounds__(256) void k_gemm(
    const bf16* __restrict__ A,
    const bf16* __restrict__ B0, const bf16* __restrict__ B1, const bf16* __restrict__ B2,
    const float* __restrict__ c0, const float* __restrict__ c1, const float* __restrict__ c2,
    float* __restrict__ D0, float* __restrict__ D1, float* __restrict__ D2) {
    const int N = 2048, K = 2048;
    const bf16* Bt = blockIdx.z == 0 ? B0 : (blockIdx.z == 1 ? B1 : B2);
    const float* bias = blockIdx.z == 0 ? c0 : (blockIdx.z == 1 ? c1 : c2);
    float* D = blockIdx.z == 0 ? D0 : (blockIdx.z == 1 ? D1 : D2);
    __shared__ bf16 Al[128][40];
    __shared__ bf16 Bl[128][40];
    int t = threadIdx.x;
    int lane = t & 63, w = t >> 6;
    int l15 = lane & 15, g = lane >> 4;
    int wr = w >> 1, wc = w & 1;
    int m0 = blockIdx.y * 128, n0 = blockIdx.x * 128;
    f32x4 acc[4][4] = {};
    int r1 = t >> 2, s1 = t & 3;
    for (int k0 = 0; k0 < K; k0 += 32) {
        bf16x8 a0 = *(const bf16x8*)&A[(size_t)(m0 + r1) * K + k0 + s1 * 8];
        bf16x8 a1 = *(const bf16x8*)&A[(size_t)(m0 + r1 + 64) * K + k0 + s1 * 8];
        bf16x8 b0 = *(const bf16x8*)&Bt[(size_t)(n0 + r1) * K + k0 + s1 * 8];
        bf16x8 b1 = *(const bf16x8*)&Bt[(size_t)(n0 + r1 + 64) * K + k0 + s1 * 8];
        *(bf16x8*)&Al[r1][s1 * 8] = a0;
        *(bf16x8*)&Al[r1 + 64][s1 * 8] = a1;
        *(bf16x8*)&Bl[r1][s1 * 8] = b0;
        *(bf16x8*)&Bl[r1 + 64][s1 * 8] = b1;
        __syncthreads();
        bf16x8 af[4], bfr[4];
#pragma unroll
        for (int i = 0; i < 4; i++) af[i] = *(const bf16x8*)&Al[wr * 64 + i * 16 + l15][g * 8];
#pragma unroll
        for (int i = 0; i < 4; i++) bfr[i] = *(const bf16x8*)&Bl[wc * 64 + i * 16 + l15][g * 8];
#pragma unroll
        for (int mi = 0; mi < 4; mi++)
#pragma unroll
            for (int ni = 0; ni < 4; ni++)
                acc[mi][ni] = MFMA16(af[mi], bfr[ni], acc[mi][ni]);
        __syncthreads();
    }
#pragma unroll
    for (int mi = 0; mi < 4; mi++) {
#pragma unroll
        for (int ni = 0; ni < 4; ni++) {
            int n = n0 + wc * 64 + ni * 16 + l15;
            float bv = bias[n];
#pragma unroll
            for (int r = 0; r < 4; r++) {
                int m = m0 + wr * 64 + mi * 16 + g * 4 + r;
                D[(size_t)m * N + n] = acc[mi][ni][r] + bv;
            }
        }
    }
}

// ---------------- rmsnorm + rope: raw fp32 rows -> bf16 head-major Q/K ----------------
__global__ __launch_bounds__(256) void k_normrope(
    const float* __restrict__ qraw, const float* __restrict__ kraw,
    const float* __restrict__ gq, const float* __restrict__ gk,
    const float* __restrict__ theta,
    bf16* __restrict__ Qb, bf16* __restrict__ Kb) {
    int l = blockIdx.x, t = threadIdx.x;
    int lane = t & 63, w = t >> 6;
    int c = t * 8;
    float qv[8], kv[8];
    const float4* qp = (const float4*)(qraw + (size_t)l * 2048 + c);
    const float4* kp = (const float4*)(kraw + (size_t)l * 2048 + c);
    float4 a;
    a = qp[0]; qv[0] = a.x; qv[1] = a.y; qv[2] = a.z; qv[3] = a.w;
    a = qp[1]; qv[4] = a.x; qv[5] = a.y; qv[6] = a.z; qv[7] = a.w;
    a = kp[0]; kv[0] = a.x; kv[1] = a.y; kv[2] = a.z; kv[3] = a.w;
    a = kp[1]; kv[4] = a.x; kv[5] = a.y; kv[6] = a.z; kv[7] = a.w;
    float ssq = 0.f, ssk = 0.f;
#pragma unroll
    for (int j = 0; j < 8; j++) { ssq += qv[j] * qv[j]; ssk += kv[j] * kv[j]; }
#pragma unroll
    for (int m = 1; m < 64; m <<= 1) { ssq += __shfl_xor(ssq, m); ssk += __shfl_xor(ssk, m); }
    __shared__ float rq[4], rk[4];
    if (lane == 0) { rq[w] = ssq; rk[w] = ssk; }
    __syncthreads();
    ssq = rq[0] + rq[1] + rq[2] + rq[3];
    ssk = rk[0] + rk[1] + rk[2] + rk[3];
    float iq = rsqrtf(ssq * (1.0f / 2048.0f) + 1e-6f);
    float ik = rsqrtf(ssk * (1.0f / 2048.0f) + 1e-6f);
#pragma unroll
    for (int j = 0; j < 8; j++) { qv[j] *= iq * gq[c + j]; kv[j] *= ik * gk[c + j]; }
    int h = c >> 7, dd = c & 127;
    bf16x8 qo, ko;
    const float SC = 0.088388347648318447f;  // 1/sqrt(128)
#pragma unroll
    for (int p = 0; p < 4; p++) {
        float th = theta[l * 64 + (dd >> 1) + p];
        float sn, cs;
        __sincosf(th, &sn, &cs);
        float qr = qv[2 * p] * cs - qv[2 * p + 1] * sn;
        float qi = qv[2 * p] * sn + qv[2 * p + 1] * cs;
        float kr = kv[2 * p] * cs - kv[2 * p + 1] * sn;
        float ki = kv[2 * p] * sn + kv[2 * p + 1] * cs;
        qo[2 * p] = (bf16)(qr * SC); qo[2 * p + 1] = (bf16)(qi * SC);
        ko[2 * p] = (bf16)kr;        ko[2 * p + 1] = (bf16)ki;
    }
    *(bf16x8*)&Qb[(size_t)h * 131072 + (size_t)l * 128 + dd] = qo;
    *(bf16x8*)&Kb[(size_t)h * 1048576 + (size_t)l * 128 + dd] = ko;
}

// ---------------- V transpose: [s][n*128+d] fp32 -> Vt[n][d][s] bf16 ----------------
__global__ __launch_bounds__(256) void k_vtrans(
    const float* __restrict__ vraw, const float* __restrict__ cache_v, bf16* __restrict__ Vt) {
    int st = blockIdx.x;   // 0..127
    int n = blockIdx.y;    // 0..15
    int s0 = st * 64;
    const float* src = (s0 < 1024) ? (vraw + (size_t)s0 * 2048) : (cache_v + (size_t)s0 * 2048);
    __shared__ bf16 lt[64][132];
    int t = threadIdx.x;
#pragma unroll
    for (int j = 0; j < 8; j++) {
        int idx = t + 256 * j;        // 0..2047
        int i = idx >> 5;             // s-local 0..63
        int d4 = (idx & 31) << 2;
        float4 v = *(const float4*)&src[(size_t)i * 2048 + n * 128 + d4];
        lt[i][d4] = (bf16)v.x; lt[i][d4 + 1] = (bf16)v.y;
        lt[i][d4 + 2] = (bf16)v.z; lt[i][d4 + 3] = (bf16)v.w;
    }
    __syncthreads();
    int d = t >> 1, sh = (t & 1) << 5;
    bf16* dst = Vt + (size_t)n * 1048576 + (size_t)d * 8192 + s0 + sh;
#pragma unroll
    for (int q = 0; q < 4; q++) {
        bf16x8 o;
#pragma unroll
        for (int e = 0; e < 8; e++) o[e] = lt[sh + q * 8 + e][d];
        *(bf16x8*)&dst[q * 8] = o;
    }
}

// ---------------- cache_k repack: [s][n][d] fp32 -> Kb[n][s][d] bf16 (s >= 1024) ----------------
__global__ __launch_bounds__(256) void k_repack_k(const float* __restrict__ cache_k, bf16* __restrict__ Kb) {
    int s = 1024 + blockIdx.x;
    int t = threadIdx.x;
    int e = t * 8;
    int n = e >> 7, d = e & 127;
    const float4* p = (const float4*)&cache_k[(size_t)s * 2048 + e];
    float4 a = p[0], b = p[1];
    bf16x8 v;
    v[0] = (bf16)a.x; v[1] = (bf16)a.y; v[2] = (bf16)a.z; v[3] = (bf16)a.w;
    v[4] = (bf16)b.x; v[5] = (bf16)b.y; v[6] = (bf16)b.z; v[7] = (bf16)b.w;
    *(bf16x8*)&Kb[(size_t)n * 1048576 + (size_t)s * 128 + d] = v;
}

// ---------------- flash attention ----------------
__global__ __launch_bounds__(256) void k_flash(
    const bf16* __restrict__ Qb, const bf16* __restrict__ Kb, const bf16* __restrict__ Vt,
    bf16* __restrict__ Ob) {
    int h = blockIdx.y;
    int q0 = blockIdx.x * 64;
    int t = threadIdx.x, lane = t & 63, w = t >> 6;
    int l15 = lane & 15, g = lane >> 4;
    __shared__ bf16 Kl[32][136];
    __shared__ bf16 Vl[128][40];
    __shared__ bf16 Pl[4][16][40];
    bf16x8 qf[4];
    int qrow = q0 + w * 16 + l15;
#pragma unroll
    for (int kk = 0; kk < 4; kk++)
        qf[kk] = *(const bf16x8*)&Qb[(size_t)h * 131072 + (size_t)qrow * 128 + kk * 32 + g * 8];
    f32x4 o[8] = {};
    float mm[4], ll[4];
#pragma unroll
    for (int r = 0; r < 4; r++) { mm[r] = -1e30f; ll[r] = 0.f; }
    const bf16* Kh = Kb + (size_t)h * 1048576;
    const bf16* Vh = Vt + (size_t)h * 1048576;
    for (int s0 = 0; s0 < 8192; s0 += 32) {
#pragma unroll
        for (int j = 0; j < 2; j++) {
            int idx = t + 256 * j;
            int row = idx >> 4, seg = idx & 15;
            *(bf16x8*)&Kl[row][seg * 8] = *(const bf16x8*)&Kh[(size_t)(s0 + row) * 128 + seg * 8];
        }
#pragma unroll
        for (int j = 0; j < 2; j++) {
            int idx = t + 256 * j;
            int d = idx >> 2, seg = idx & 3;
            *(bf16x8*)&Vl[d][seg * 8] = *(const bf16x8*)&Vh[(size_t)d * 8192 + s0 + seg * 8];
        }
        __syncthreads();
        f32x4 sc0 = {}, sc1 = {};
#pragma unroll
        for (int kk = 0; kk < 4; kk++) {
            bf16x8 k0 = *(const bf16x8*)&Kl[l15][kk * 32 + g * 8];
            bf16x8 k1 = *(const bf16x8*)&Kl[16 + l15][kk * 32 + g * 8];
            sc0 = MFMA16(qf[kk], k0, sc0);
            sc1 = MFMA16(qf[kk], k1, sc1);
        }
#pragma unroll
        for (int r = 0; r < 4; r++) {
            float tm = fmaxf(sc0[r], sc1[r]);
            tm = fmaxf(tm, __shfl_xor(tm, 1));
            tm = fmaxf(tm, __shfl_xor(tm, 2));
            tm = fmaxf(tm, __shfl_xor(tm, 4));
            tm = fmaxf(tm, __shfl_xor(tm, 8));
            float mnew = fmaxf(mm[r], tm);
            float alpha = __expf(mm[r] - mnew);
            float p0 = __expf(sc0[r] - mnew);
            float p1 = __expf(sc1[r] - mnew);
            float ts = p0 + p1;
            ts += __shfl_xor(ts, 1);
            ts += __shfl_xor(ts, 2);
            ts += __shfl_xor(ts, 4);
            ts += __shfl_xor(ts, 8);
            ll[r] = ll[r] * alpha + ts;
            mm[r] = mnew;
            Pl[w][g * 4 + r][l15] = (bf16)p0;
            Pl[w][g * 4 + r][16 + l15] = (bf16)p1;
#pragma unroll
            for (int nc = 0; nc < 8; nc++) o[nc][r] *= alpha;
        }
        bf16x8 pf = *(const bf16x8*)&Pl[w][l15][g * 8];
#pragma unroll
        for (int nc = 0; nc < 8; nc++) {
            bf16x8 vf = *(const bf16x8*)&Vl[nc * 16 + l15][g * 8];
            o[nc] = MFMA16(pf, vf, o[nc]);
        }
        __syncthreads();
    }
#pragma unroll
    for (int nc = 0; nc < 8; nc++) {
#pragma unroll
        for (int r = 0; r < 4; r++) {
            float val = o[nc][r] / ll[r];
            Ob[(size_t)(q0 + w * 16 + g * 4 + r) * 2048 + h * 128 + nc * 16 + l15] = (bf16)val;
        }
    }
}

extern "C" void kernel_launch(void* const* d_in, const int* in_sizes, int n_in,
                              void* d_out, int out_size, void* d_ws, size_t ws_size,
                              hipStream_t stream) {
    const float* x       = (const float*)d_in[0];
    const float* cache_k = (const float*)d_in[1];
    const float* cache_v = (const float*)d_in[2];
    const float* theta   = (const float*)d_in[5];
    const float* Wq = (const float*)d_in[6];
    const float* bq = (const float*)d_in[7];
    const float* Wk = (const float*)d_in[8];
    const float* bk = (const float*)d_in[9];
    const float* Wv = (const float*)d_in[10];
    const float* bv = (const float*)d_in[11];
    const float* Wo = (const float*)d_in[12];
    const float* bo = (const float*)d_in[13];
    const float* gq = (const float*)d_in[14];
    const float* gk = (const float*)d_in[15];
    float* out = (float*)d_out;

    // ws layout (132 MB total)
    bf16* xbf = (bf16*)d_ws;                 // 2M  (4 MB)
    bf16* WqT = xbf + 2097152;               // 4M  (8 MB) each
    bf16* WkT = WqT + 4194304;
    bf16* WvT = WkT + 4194304;
    bf16* WoT = WvT + 4194304;
    float* qraw = (float*)(WoT + 4194304);   // 2M fp32 (8 MB) each
    float* kraw = qraw + 2097152;
    float* vraw = kraw + 2097152;
    bf16* Qb = (bf16*)(vraw + 2097152);      // [16][1024][128]
    bf16* Kb = Qb + 2097152;                 // [16][8192][128]
    bf16* Vt = Kb + 16777216;                // [16][128][8192]
    bf16* Ob = Vt + 16777216;                // [1024][2048]

    k_cvt_x<<<1024, 256, 0, stream>>>(x, xbf);
    k_wt<<<dim3(32, 32), 256, 0, stream>>>(Wq, WqT);
    k_wt<<<dim3(32, 32), 256, 0, stream>>>(Wk, WkT);
    k_wt<<<dim3(32, 32), 256, 0, stream>>>(Wv, WvT);
    k_wt<<<dim3(32, 32), 256, 0, stream>>>(Wo, WoT);
    k_gemm<<<dim3(16, 8, 3), 256, 0, stream>>>(xbf, WqT, WkT, WvT, bq, bk, bv, qraw, kraw, vraw);
    k_normrope<<<1024, 256, 0, stream>>>(qraw, kraw, gq, gk, theta, Qb, Kb);
    k_vtrans<<<dim3(128, 16), 256, 0, stream>>>(vraw, cache_v, Vt);
    k_repack_k<<<7168, 256, 0, stream>>>(cache_k, Kb);
    k_flash<<<dim3(16, 16), 256, 0, stream>>>(Qb, Kb, Vt, Ob);
    k_gemm<<<dim3(16, 8, 1), 256, 0, stream>>>(Ob, WoT, WoT, WoT, bo, bo, bo, out, out, out);
}

// Round 2
// 392.513 us; speedup vs baseline: 1.8718x; 1.8718x over previous
//
#include <hip/hip_runtime.h>

typedef __bf16 bf16;
typedef bf16 bf16x8 __attribute__((ext_vector_type(8)));
typedef bf16 bf16x4 __attribute__((ext_vector_type(4)));
typedef float f32x4 __attribute__((ext_vector_type(4)));

#define MFMA16(a, b, c) __builtin_amdgcn_mfma_f32_16x16x32_bf16(a, b, c, 0, 0, 0)

// ---------------- x -> bf16 ----------------
__global__ __launch_bounds__(256) void k_cvt_x(const float* __restrict__ x, bf16* __restrict__ o) {
    int i = (blockIdx.x * 256 + threadIdx.x) * 8;
    const float4* p = (const float4*)(x + i);
    float4 a = p[0], b = p[1];
    bf16x8 v;
    v[0] = (bf16)a.x; v[1] = (bf16)a.y; v[2] = (bf16)a.z; v[3] = (bf16)a.w;
    v[4] = (bf16)b.x; v[5] = (bf16)b.y; v[6] = (bf16)b.z; v[7] = (bf16)b.w;
    *(bf16x8*)(o + i) = v;
}

// ---------------- W [K][N] fp32 -> WT [N][K] bf16 ----------------
__global__ __launch_bounds__(256) void k_wt(const float* __restrict__ W, bf16* __restrict__ WT) {
    __shared__ bf16 lt[64][72];
    int t = threadIdx.x;
    int n0 = blockIdx.x * 64, k0 = blockIdx.y * 64;
#pragma unroll
    for (int j = 0; j < 4; j++) {
        int idx = t + 256 * j;
        int r = idx >> 4;             // k row 0..63
        int c4 = (idx & 15) << 2;     // n col
        float4 v = *(const float4*)&W[(size_t)(k0 + r) * 2048 + n0 + c4];
        lt[r][c4] = (bf16)v.x; lt[r][c4 + 1] = (bf16)v.y;
        lt[r][c4 + 2] = (bf16)v.z; lt[r][c4 + 3] = (bf16)v.w;
    }
    __syncthreads();
#pragma unroll
    for (int j = 0; j < 4; j++) {
        int idx = t + 256 * j;
        int n = idx >> 4;
        int k4 = (idx & 15) << 2;
        bf16x4 o;
        o[0] = lt[k4][n]; o[1] = lt[k4 + 1][n]; o[2] = lt[k4 + 2][n]; o[3] = lt[k4 + 3][n];
        *(bf16x4*)&WT[(size_t)(n0 + n) * 2048 + k0 + k4] = o;
    }
}

// ---------------- GEMM: C[M=1024][N=2048] = A[M][K=2048](bf16) * Bt[N][K]^T + bias, fp32 out ----
__global__ __launch_bounds__(256) void k_gemm(
    const bf16* __restrict__ A,
    const bf16* __restrict__ B0, const bf16* __restrict__ B1, const bf16* __restrict__ B2,
    const float* __restrict__ c0, const float* __restrict__ c1, const float* __restrict__ c2,
    float* __restrict__ D0, float* __restrict__ D1, float* __restrict__ D2) {
    const int N = 2048, K = 2048;
    const bf16* Bt = blockIdx.z == 0 ? B0 : (blockIdx.z == 1 ? B1 : B2);
    const float* bias = blockIdx.z == 0 ? c0 : (blockIdx.z == 1 ? c1 : c2);
    float* D = blockIdx.z == 0 ? D0 : (blockIdx.z == 1 ? D1 : D2);
    __shared__ bf16 Al[128][40];
    __shared__ bf16 Bl[128][40];
    int t = threadIdx.x;
    int lane = t & 63, w = t >> 6;
    int l15 = lane & 15, g = lane >> 4;
    int wr = w >> 1, wc = w & 1;
    int m0 = blockIdx.y * 128, n0 = blockIdx.x * 128;
    f32x4 acc[4][4] = {};
    int r1 = t >> 2, s1 = t & 3;
    for (int k0 = 0; k0 < K; k0 += 32) {
        bf16x8 a0 = *(const bf16x8*)&A[(size_t)(m0 + r1) * K + k0 + s1 * 8];
        bf16x8 a1 = *(const bf16x8*)&A[(size_t)(m0 + r1 + 64) * K + k0 + s1 * 8];
        bf16x8 b0 = *(const bf16x8*)&Bt[(size_t)(n0 + r1) * K + k0 + s1 * 8];
        bf16x8 b1 = *(const bf16x8*)&Bt[(size_t)(n0 + r1 + 64) * K + k0 + s1 * 8];
        *(bf16x8*)&Al[r1][s1 * 8] = a0;
        *(bf16x8*)&Al[r1 + 64][s1 * 8] = a1;
        *(bf16x8*)&Bl[r1][s1 * 8] = b0;
        *(bf16x8*)&Bl[r1 + 64][s1 * 8] = b1;
        __syncthreads();
        bf16x8 af[4], bfr[4];
#pragma unroll
        for (int i = 0; i < 4; i++) af[i] = *(const bf16x8*)&Al[wr * 64 + i * 16 + l15][g * 8];
#pragma unroll
        for (int i = 0; i < 4; i++) bfr[i] = *(const bf16x8*)&Bl[wc * 64 + i * 16 + l15][g * 8];
#pragma unroll
        for (int mi = 0; mi < 4; mi++)
#pragma unroll
            for (int ni = 0; ni < 4; ni++)
                acc[mi][ni] = MFMA16(af[mi], bfr[ni], acc[mi][ni]);
        __syncthreads();
    }
#pragma unroll
    for (int mi = 0; mi < 4; mi++) {
#pragma unroll
        for (int ni = 0; ni < 4; ni++) {
            int n = n0 + wc * 64 + ni * 16 + l15;
            float bv = bias[n];
#pragma unroll
            for (int r = 0; r < 4; r++) {
                int m = m0 + wr * 64 + mi * 16 + g * 4 + r;
                D[(size_t)m * N + n] = acc[mi][ni][r] + bv;
            }
        }
    }
}

// ---------------- rmsnorm + rope: raw fp32 rows -> bf16 head-major Q/K ----------------
__global__ __launch_bounds__(256) void k_normrope(
    const float* __restrict__ qraw, const float* __restrict__ kraw,
    const float* __restrict__ gq, const float* __restrict__ gk,
    const float* __restrict__ theta,
    bf16* __restrict__ Qb, bf16* __restrict__ Kb) {
    int l = blockIdx.x, t = threadIdx.x;
    int lane = t & 63, w = t >> 6;
    int c = t * 8;
    float qv[8], kv[8];
    const float4* qp = (const float4*)(qraw + (size_t)l * 2048 + c);
    const float4* kp = (const float4*)(kraw + (size_t)l * 2048 + c);
    float4 a;
    a = qp[0]; qv[0] = a.x; qv[1] = a.y; qv[2] = a.z; qv[3] = a.w;
    a = qp[1]; qv[4] = a.x; qv[5] = a.y; qv[6] = a.z; qv[7] = a.w;
    a = kp[0]; kv[0] = a.x; kv[1] = a.y; kv[2] = a.z; kv[3] = a.w;
    a = kp[1]; kv[4] = a.x; kv[5] = a.y; kv[6] = a.z; kv[7] = a.w;
    float ssq = 0.f, ssk = 0.f;
#pragma unroll
    for (int j = 0; j < 8; j++) { ssq += qv[j] * qv[j]; ssk += kv[j] * kv[j]; }
#pragma unroll
    for (int m = 1; m < 64; m <<= 1) { ssq += __shfl_xor(ssq, m); ssk += __shfl_xor(ssk, m); }
    __shared__ float rq[4], rk[4];
    if (lane == 0) { rq[w] = ssq; rk[w] = ssk; }
    __syncthreads();
    ssq = rq[0] + rq[1] + rq[2] + rq[3];
    ssk = rk[0] + rk[1] + rk[2] + rk[3];
    float iq = rsqrtf(ssq * (1.0f / 2048.0f) + 1e-6f);
    float ik = rsqrtf(ssk * (1.0f / 2048.0f) + 1e-6f);
#pragma unroll
    for (int j = 0; j < 8; j++) { qv[j] *= iq * gq[c + j]; kv[j] *= ik * gk[c + j]; }
    int h = c >> 7, dd = c & 127;
    bf16x8 qo, ko;
    const float SC = 0.088388347648318447f;  // 1/sqrt(128)
#pragma unroll
    for (int p = 0; p < 4; p++) {
        float th = theta[l * 64 + (dd >> 1) + p];
        float sn, cs;
        __sincosf(th, &sn, &cs);
        float qr = qv[2 * p] * cs - qv[2 * p + 1] * sn;
        float qi = qv[2 * p] * sn + qv[2 * p + 1] * cs;
        float kr = kv[2 * p] * cs - kv[2 * p + 1] * sn;
        float ki = kv[2 * p] * sn + kv[2 * p + 1] * cs;
        qo[2 * p] = (bf16)(qr * SC); qo[2 * p + 1] = (bf16)(qi * SC);
        ko[2 * p] = (bf16)kr;        ko[2 * p + 1] = (bf16)ki;
    }
    *(bf16x8*)&Qb[(size_t)h * 131072 + (size_t)l * 128 + dd] = qo;
    *(bf16x8*)&Kb[(size_t)h * 1048576 + (size_t)l * 128 + dd] = ko;
}

// ---------------- V transpose: [s][n*128+d] fp32 -> Vt[n][d][s] bf16 ----------------
__global__ __launch_bounds__(256) void k_vtrans(
    const float* __restrict__ vraw, const float* __restrict__ cache_v, bf16* __restrict__ Vt) {
    int st = blockIdx.x;   // 0..127
    int n = blockIdx.y;    // 0..15
    int s0 = st * 64;
    const float* src = (s0 < 1024) ? (vraw + (size_t)s0 * 2048) : (cache_v + (size_t)s0 * 2048);
    __shared__ bf16 lt[64][132];
    int t = threadIdx.x;
#pragma unroll
    for (int j = 0; j < 8; j++) {
        int idx = t + 256 * j;        // 0..2047
        int i = idx >> 5;             // s-local 0..63
        int d4 = (idx & 31) << 2;
        float4 v = *(const float4*)&src[(size_t)i * 2048 + n * 128 + d4];
        lt[i][d4] = (bf16)v.x; lt[i][d4 + 1] = (bf16)v.y;
        lt[i][d4 + 2] = (bf16)v.z; lt[i][d4 + 3] = (bf16)v.w;
    }
    __syncthreads();
    int d = t >> 1, sh = (t & 1) << 5;
    bf16* dst = Vt + (size_t)n * 1048576 + (size_t)d * 8192 + s0 + sh;
#pragma unroll
    for (int q = 0; q < 4; q++) {
        bf16x8 o;
#pragma unroll
        for (int e = 0; e < 8; e++) o[e] = lt[sh + q * 8 + e][d];
        *(bf16x8*)&dst[q * 8] = o;
    }
}

// ---------------- cache_k repack: [s][n][d] fp32 -> Kb[n][s][d] bf16 (s >= 1024) ----------------
__global__ __launch_bounds__(256) void k_repack_k(const float* __restrict__ cache_k, bf16* __restrict__ Kb) {
    int s = 1024 + blockIdx.x;
    int t = threadIdx.x;
    int e = t * 8;
    int n = e >> 7, d = e & 127;
    const float4* p = (const float4*)&cache_k[(size_t)s * 2048 + e];
    float4 a = p[0], b = p[1];
    bf16x8 v;
    v[0] = (bf16)a.x; v[1] = (bf16)a.y; v[2] = (bf16)a.z; v[3] = (bf16)a.w;
    v[4] = (bf16)b.x; v[5] = (bf16)b.y; v[6] = (bf16)b.z; v[7] = (bf16)b.w;
    *(bf16x8*)&Kb[(size_t)n * 1048576 + (size_t)s * 128 + d] = v;
}

// ---------------- flash attention, split-S, KVBLK=64 ----------------
// grid (16 qblk, 16 heads, 3 splits); partial O (fp32) + (m,l) per split.
__global__ __launch_bounds__(256) void k_flash(
    const bf16* __restrict__ Qb, const bf16* __restrict__ Kb, const bf16* __restrict__ Vt,
    float* __restrict__ Opart, float2* __restrict__ MLpart) {
    int h = blockIdx.y, z = blockIdx.z;
    int q0 = blockIdx.x * 64;
    int t0 = z * 43;
    int cnt = (z == 2) ? 42 : 43;
    int t = threadIdx.x, lane = t & 63, w = t >> 6;
    int l15 = lane & 15, g = lane >> 4;
    __shared__ bf16 Kl[64][136];
    __shared__ bf16 Vl[128][72];
    __shared__ bf16 Pl[4][16][72];
    bf16x8 qf[4];
    int qrow = q0 + w * 16 + l15;
#pragma unroll
    for (int kk = 0; kk < 4; kk++)
        qf[kk] = *(const bf16x8*)&Qb[(size_t)h * 131072 + (size_t)qrow * 128 + kk * 32 + g * 8];
    f32x4 o[8] = {};
    float mm[4], ll[4];
#pragma unroll
    for (int r = 0; r < 4; r++) { mm[r] = -1e30f; ll[r] = 0.f; }
    const bf16* Kh = Kb + (size_t)h * 1048576;
    const bf16* Vh = Vt + (size_t)h * 1048576;
    for (int it = 0; it < cnt; ++it) {
        int s0 = (t0 + it) * 64;
#pragma unroll
        for (int j = 0; j < 4; j++) {
            int idx = t + 256 * j;
            int row = idx >> 4, seg = idx & 15;
            *(bf16x8*)&Kl[row][seg * 8] = *(const bf16x8*)&Kh[(size_t)(s0 + row) * 128 + seg * 8];
        }
#pragma unroll
        for (int j = 0; j < 4; j++) {
            int idx = t + 256 * j;
            int d = idx >> 3, sg = idx & 7;
            *(bf16x8*)&Vl[d][sg * 8] = *(const bf16x8*)&Vh[(size_t)d * 8192 + s0 + sg * 8];
        }
        __syncthreads();
        f32x4 sc[4] = {};
#pragma unroll
        for (int kk = 0; kk < 4; kk++) {
            bf16x8 af = qf[kk];
#pragma unroll
            for (int st = 0; st < 4; st++) {
                bf16x8 kf = *(const bf16x8*)&Kl[st * 16 + l15][kk * 32 + g * 8];
                sc[st] = MFMA16(af, kf, sc[st]);
            }
        }
#pragma unroll
        for (int r = 0; r < 4; r++) {
            float tm = fmaxf(fmaxf(sc[0][r], sc[1][r]), fmaxf(sc[2][r], sc[3][r]));
            tm = fmaxf(tm, __shfl_xor(tm, 1));
            tm = fmaxf(tm, __shfl_xor(tm, 2));
            tm = fmaxf(tm, __shfl_xor(tm, 4));
            tm = fmaxf(tm, __shfl_xor(tm, 8));
            float mnew = fmaxf(mm[r], tm);
            float alpha = __expf(mm[r] - mnew);
            float p0 = __expf(sc[0][r] - mnew);
            float p1 = __expf(sc[1][r] - mnew);
            float p2 = __expf(sc[2][r] - mnew);
            float p3 = __expf(sc[3][r] - mnew);
            float ts = p0 + p1 + p2 + p3;
            ts += __shfl_xor(ts, 1);
            ts += __shfl_xor(ts, 2);
            ts += __shfl_xor(ts, 4);
            ts += __shfl_xor(ts, 8);
            ll[r] = ll[r] * alpha + ts;
            mm[r] = mnew;
            int qr = g * 4 + r;
            Pl[w][qr][l15]      = (bf16)p0;
            Pl[w][qr][16 + l15] = (bf16)p1;
            Pl[w][qr][32 + l15] = (bf16)p2;
            Pl[w][qr][48 + l15] = (bf16)p3;
#pragma unroll
            for (int nc = 0; nc < 8; nc++) o[nc][r] *= alpha;
        }
        bf16x8 pa0 = *(const bf16x8*)&Pl[w][l15][g * 8];
        bf16x8 pa1 = *(const bf16x8*)&Pl[w][l15][32 + g * 8];
#pragma unroll
        for (int nc = 0; nc < 8; nc++) {
            bf16x8 vf0 = *(const bf16x8*)&Vl[nc * 16 + l15][g * 8];
            o[nc] = MFMA16(pa0, vf0, o[nc]);
        }
#pragma unroll
        for (int nc = 0; nc < 8; nc++) {
            bf16x8 vf1 = *(const bf16x8*)&Vl[nc * 16 + l15][32 + g * 8];
            o[nc] = MFMA16(pa1, vf1, o[nc]);
        }
        __syncthreads();
    }
    size_t base = (size_t)(z * 16 + h) * 1024 + q0 + w * 16;
#pragma unroll
    for (int nc = 0; nc < 8; nc++) {
#pragma unroll
        for (int r = 0; r < 4; r++) {
            Opart[(base + g * 4 + r) * 128 + nc * 16 + l15] = o[nc][r];
        }
    }
    if (l15 == 0) {
#pragma unroll
        for (int r = 0; r < 4; r++) {
            MLpart[base + g * 4 + r] = make_float2(mm[r], ll[r]);
        }
    }
}

// ---------------- combine partials -> Ob bf16 [q][h*128+d] ----------------
__global__ __launch_bounds__(256) void k_combine(
    const float* __restrict__ Opart, const float2* __restrict__ MLpart,
    bf16* __restrict__ Ob) {
    int q = blockIdx.x, t = threadIdx.x;
    int h = t >> 4, d0 = (t & 15) * 8;
    float m[3], l[3];
#pragma unroll
    for (int z = 0; z < 3; z++) {
        float2 v = MLpart[(size_t)(z * 16 + h) * 1024 + q];
        m[z] = v.x; l[z] = v.y;
    }
    float M = fmaxf(m[0], fmaxf(m[1], m[2]));
    float e[3];
#pragma unroll
    for (int z = 0; z < 3; z++) e[z] = __expf(m[z] - M);
    float inv = 1.0f / (e[0] * l[0] + e[1] * l[1] + e[2] * l[2]);
    float acc[8] = {};
#pragma unroll
    for (int z = 0; z < 3; z++) {
        const float4* p = (const float4*)&Opart[((size_t)(z * 16 + h) * 1024 + q) * 128 + d0];
        float4 a = p[0], b = p[1];
        float s = e[z] * inv;
        acc[0] += a.x * s; acc[1] += a.y * s; acc[2] += a.z * s; acc[3] += a.w * s;
        acc[4] += b.x * s; acc[5] += b.y * s; acc[6] += b.z * s; acc[7] += b.w * s;
    }
    bf16x8 ov;
#pragma unroll
    for (int j = 0; j < 8; j++) ov[j] = (bf16)acc[j];
    *(bf16x8*)&Ob[(size_t)q * 2048 + h * 128 + d0] = ov;
}

extern "C" void kernel_launch(void* const* d_in, const int* in_sizes, int n_in,
                              void* d_out, int out_size, void* d_ws, size_t ws_size,
                              hipStream_t stream) {
    const float* x       = (const float*)d_in[0];
    const float* cache_k = (const float*)d_in[1];
    const float* cache_v = (const float*)d_in[2];
    const float* theta   = (const float*)d_in[5];
    const float* Wq = (const float*)d_in[6];
    const float* bq = (const float*)d_in[7];
    const float* Wk = (const float*)d_in[8];
    const float* bk = (const float*)d_in[9];
    const float* Wv = (const float*)d_in[10];
    const float* bv = (const float*)d_in[11];
    const float* Wo = (const float*)d_in[12];
    const float* bo = (const float*)d_in[13];
    const float* gq = (const float*)d_in[14];
    const float* gk = (const float*)d_in[15];
    float* out = (float*)d_out;

    // ws layout (132 MB total)
    bf16* xbf = (bf16*)d_ws;                 // 2M bf16 (4 MB); dead after QKV gemm -> reused as MLpart
    bf16* WqT = xbf + 2097152;               // 4M bf16 (8 MB) each
    bf16* WkT = WqT + 4194304;
    bf16* WvT = WkT + 4194304;
    bf16* WoT = WvT + 4194304;
    float* qraw = (float*)(WoT + 4194304);   // 2M fp32 (8 MB) each; dead after normrope/vtrans
    float* kraw = qraw + 2097152;
    float* vraw = kraw + 2097152;
    bf16* Qb = (bf16*)(vraw + 2097152);      // [16][1024][128]
    bf16* Kb = Qb + 2097152;                 // [16][8192][128]
    bf16* Vt = Kb + 16777216;                // [16][128][8192]
    bf16* Ob = Vt + 16777216;                // [1024][2048]

    // flash partials reuse dead regions:
    float* Opart = qraw;                     // [3][16][1024][128] fp32 = 24 MB (qraw+kraw+vraw)
    float2* MLpart = (float2*)xbf;           // [3][16][1024] float2 = 384 KB (in dead xbf)

    k_cvt_x<<<1024, 256, 0, stream>>>(x, xbf);
    k_wt<<<dim3(32, 32), 256, 0, stream>>>(Wq, WqT);
    k_wt<<<dim3(32, 32), 256, 0, stream>>>(Wk, WkT);
    k_wt<<<dim3(32, 32), 256, 0, stream>>>(Wv, WvT);
    k_wt<<<dim3(32, 32), 256, 0, stream>>>(Wo, WoT);
    k_gemm<<<dim3(16, 8, 3), 256, 0, stream>>>(xbf, WqT, WkT, WvT, bq, bk, bv, qraw, kraw, vraw);
    k_normrope<<<1024, 256, 0, stream>>>(qraw, kraw, gq, gk, theta, Qb, Kb);
    k_vtrans<<<dim3(128, 16), 256, 0, stream>>>(vraw, cache_v, Vt);
    k_repack_k<<<7168, 256, 0, stream>>>(cache_k, Kb);
    k_flash<<<dim3(16, 16, 3), 256, 0, stream>>>(Qb, Kb, Vt, Opart, MLpart);
    k_combine<<<1024, 256, 0, stream>>>(Opart, MLpart, Ob);
    k_gemm<<<dim3(16, 8, 1), 256, 0, stream>>>(Ob, WoT, WoT, WoT, bo, bo, bo, out, out, out);
}

// Round 4
// 294.862 us; speedup vs baseline: 2.4916x; 1.3312x over previous
//
#include <hip/hip_runtime.h>

typedef __bf16 bf16;
typedef bf16 bf16x8 __attribute__((ext_vector_type(8)));
typedef bf16 bf16x4 __attribute__((ext_vector_type(4)));
typedef float f32x4 __attribute__((ext_vector_type(4)));
typedef float f32x16 __attribute__((ext_vector_type(16)));

#define MFMA16(a, b, c) __builtin_amdgcn_mfma_f32_16x16x32_bf16(a, b, c, 0, 0, 0)
#define MFMA32(a, b, c) __builtin_amdgcn_mfma_f32_32x32x16_bf16(a, b, c, 0, 0, 0)

__device__ __forceinline__ unsigned int pkbf(float a, float b) {
    union { bf16 h[2]; unsigned int u; } x;
    x.h[0] = (bf16)a; x.h[1] = (bf16)b;
    return x.u;
}

// ---------------- x -> bf16 ----------------
__global__ __launch_bounds__(256) void k_cvt_x(const float* __restrict__ x, bf16* __restrict__ o) {
    int i = (blockIdx.x * 256 + threadIdx.x) * 8;
    const float4* p = (const float4*)(x + i);
    float4 a = p[0], b = p[1];
    bf16x8 v;
    v[0] = (bf16)a.x; v[1] = (bf16)a.y; v[2] = (bf16)a.z; v[3] = (bf16)a.w;
    v[4] = (bf16)b.x; v[5] = (bf16)b.y; v[6] = (bf16)b.z; v[7] = (bf16)b.w;
    *(bf16x8*)(o + i) = v;
}

// ---------------- W [K][N] fp32 -> WT [N][K] bf16 ----------------
__global__ __launch_bounds__(256) void k_wt(const float* __restrict__ W, bf16* __restrict__ WT) {
    __shared__ bf16 lt[64][72];
    int t = threadIdx.x;
    int n0 = blockIdx.x * 64, k0 = blockIdx.y * 64;
#pragma unroll
    for (int j = 0; j < 4; j++) {
        int idx = t + 256 * j;
        int r = idx >> 4;
        int c4 = (idx & 15) << 2;
        float4 v = *(const float4*)&W[(size_t)(k0 + r) * 2048 + n0 + c4];
        lt[r][c4] = (bf16)v.x; lt[r][c4 + 1] = (bf16)v.y;
        lt[r][c4 + 2] = (bf16)v.z; lt[r][c4 + 3] = (bf16)v.w;
    }
    __syncthreads();
#pragma unroll
    for (int j = 0; j < 4; j++) {
        int idx = t + 256 * j;
        int n = idx >> 4;
        int k4 = (idx & 15) << 2;
        bf16x4 o;
        o[0] = lt[k4][n]; o[1] = lt[k4 + 1][n]; o[2] = lt[k4 + 2][n]; o[3] = lt[k4 + 3][n];
        *(bf16x4*)&WT[(size_t)(n0 + n) * 2048 + k0 + k4] = o;
    }
}

// ---------------- GEMM: C[1024][2048] = A * Bt^T + bias, fp32 out ----
__global__ __launch_bounds__(256) void k_gemm(
    const bf16* __restrict__ A,
    const bf16* __restrict__ B0, const bf16* __restrict__ B1, const bf16* __restrict__ B2,
    const float* __restrict__ c0, const float* __restrict__ c1, const float* __restrict__ c2,
    float* __restrict__ D0, float* __restrict__ D1, float* __restrict__ D2) {
    const int N = 2048, K = 2048;
    const bf16* Bt = blockIdx.z == 0 ? B0 : (blockIdx.z == 1 ? B1 : B2);
    const float* bias = blockIdx.z == 0 ? c0 : (blockIdx.z == 1 ? c1 : c2);
    float* D = blockIdx.z == 0 ? D0 : (blockIdx.z == 1 ? D1 : D2);
    __shared__ bf16 Al[128][40];
    __shared__ bf16 Bl[128][40];
    int t = threadIdx.x;
    int lane = t & 63, w = t >> 6;
    int l15 = lane & 15, g = lane >> 4;
    int wr = w >> 1, wc = w & 1;
    int m0 = blockIdx.y * 128, n0 = blockIdx.x * 128;
    f32x4 acc[4][4] = {};
    int r1 = t >> 2, s1 = t & 3;
    for (int k0 = 0; k0 < K; k0 += 32) {
        bf16x8 a0 = *(const bf16x8*)&A[(size_t)(m0 + r1) * K + k0 + s1 * 8];
        bf16x8 a1 = *(const bf16x8*)&A[(size_t)(m0 + r1 + 64) * K + k0 + s1 * 8];
        bf16x8 b0 = *(const bf16x8*)&Bt[(size_t)(n0 + r1) * K + k0 + s1 * 8];
        bf16x8 b1 = *(const bf16x8*)&Bt[(size_t)(n0 + r1 + 64) * K + k0 + s1 * 8];
        *(bf16x8*)&Al[r1][s1 * 8] = a0;
        *(bf16x8*)&Al[r1 + 64][s1 * 8] = a1;
        *(bf16x8*)&Bl[r1][s1 * 8] = b0;
        *(bf16x8*)&Bl[r1 + 64][s1 * 8] = b1;
        __syncthreads();
        bf16x8 af[4], bfr[4];
#pragma unroll
        for (int i = 0; i < 4; i++) af[i] = *(const bf16x8*)&Al[wr * 64 + i * 16 + l15][g * 8];
#pragma unroll
        for (int i = 0; i < 4; i++) bfr[i] = *(const bf16x8*)&Bl[wc * 64 + i * 16 + l15][g * 8];
#pragma unroll
        for (int mi = 0; mi < 4; mi++)
#pragma unroll
            for (int ni = 0; ni < 4; ni++)
                acc[mi][ni] = MFMA16(af[mi], bfr[ni], acc[mi][ni]);
        __syncthreads();
    }
#pragma unroll
    for (int mi = 0; mi < 4; mi++) {
#pragma unroll
        for (int ni = 0; ni < 4; ni++) {
            int n = n0 + wc * 64 + ni * 16 + l15;
            float bv = bias[n];
#pragma unroll
            for (int r = 0; r < 4; r++) {
                int m = m0 + wr * 64 + mi * 16 + g * 4 + r;
                D[(size_t)m * N + n] = acc[mi][ni][r] + bv;
            }
        }
    }
}

// ---------------- rmsnorm + rope (Q scale folded with log2e) ----------------
__global__ __launch_bounds__(256) void k_normrope(
    const float* __restrict__ qraw, const float* __restrict__ kraw,
    const float* __restrict__ gq, const float* __restrict__ gk,
    const float* __restrict__ theta,
    bf16* __restrict__ Qb, bf16* __restrict__ Kb) {
    int l = blockIdx.x, t = threadIdx.x;
    int lane = t & 63, w = t >> 6;
    int c = t * 8;
    float qv[8], kv[8];
    const float4* qp = (const float4*)(qraw + (size_t)l * 2048 + c);
    const float4* kp = (const float4*)(kraw + (size_t)l * 2048 + c);
    float4 a;
    a = qp[0]; qv[0] = a.x; qv[1] = a.y; qv[2] = a.z; qv[3] = a.w;
    a = qp[1]; qv[4] = a.x; qv[5] = a.y; qv[6] = a.z; qv[7] = a.w;
    a = kp[0]; kv[0] = a.x; kv[1] = a.y; kv[2] = a.z; kv[3] = a.w;
    a = kp[1]; kv[4] = a.x; kv[5] = a.y; kv[6] = a.z; kv[7] = a.w;
    float ssq = 0.f, ssk = 0.f;
#pragma unroll
    for (int j = 0; j < 8; j++) { ssq += qv[j] * qv[j]; ssk += kv[j] * kv[j]; }
#pragma unroll
    for (int m = 1; m < 64; m <<= 1) { ssq += __shfl_xor(ssq, m); ssk += __shfl_xor(ssk, m); }
    __shared__ float rq[4], rk[4];
    if (lane == 0) { rq[w] = ssq; rk[w] = ssk; }
    __syncthreads();
    ssq = rq[0] + rq[1] + rq[2] + rq[3];
    ssk = rk[0] + rk[1] + rk[2] + rk[3];
    float iq = rsqrtf(ssq * (1.0f / 2048.0f) + 1e-6f);
    float ik = rsqrtf(ssk * (1.0f / 2048.0f) + 1e-6f);
#pragma unroll
    for (int j = 0; j < 8; j++) { qv[j] *= iq * gq[c + j]; kv[j] *= ik * gk[c + j]; }
    int h = c >> 7, dd = c & 127;
    bf16x8 qo, ko;
    // log2(e) / sqrt(128): softmax runs in base-2
    const float SC = 1.4426950408889634f / 11.313708498984761f;
#pragma unroll
    for (int p = 0; p < 4; p++) {
        float th = theta[l * 64 + (dd >> 1) + p];
        float sn, cs;
        __sincosf(th, &sn, &cs);
        float qr = qv[2 * p] * cs - qv[2 * p + 1] * sn;
        float qi = qv[2 * p] * sn + qv[2 * p + 1] * cs;
        float kr = kv[2 * p] * cs - kv[2 * p + 1] * sn;
        float ki = kv[2 * p] * sn + kv[2 * p + 1] * cs;
        qo[2 * p] = (bf16)(qr * SC); qo[2 * p + 1] = (bf16)(qi * SC);
        ko[2 * p] = (bf16)kr;        ko[2 * p + 1] = (bf16)ki;
    }
    *(bf16x8*)&Qb[(size_t)h * 131072 + (size_t)l * 128 + dd] = qo;
    *(bf16x8*)&Kb[(size_t)h * 1048576 + (size_t)l * 128 + dd] = ko;
}

// ---------------- V transpose: [s][n*128+d] fp32 -> Vt[n][d][s] bf16 ----------------
__global__ __launch_bounds__(256) void k_vtrans(
    const float* __restrict__ vraw, const float* __restrict__ cache_v, bf16* __restrict__ Vt) {
    int st = blockIdx.x;
    int n = blockIdx.y;
    int s0 = st * 64;
    const float* src = (s0 < 1024) ? (vraw + (size_t)s0 * 2048) : (cache_v + (size_t)s0 * 2048);
    __shared__ bf16 lt[64][132];
    int t = threadIdx.x;
#pragma unroll
    for (int j = 0; j < 8; j++) {
        int idx = t + 256 * j;
        int i = idx >> 5;
        int d4 = (idx & 31) << 2;
        float4 v = *(const float4*)&src[(size_t)i * 2048 + n * 128 + d4];
        lt[i][d4] = (bf16)v.x; lt[i][d4 + 1] = (bf16)v.y;
        lt[i][d4 + 2] = (bf16)v.z; lt[i][d4 + 3] = (bf16)v.w;
    }
    __syncthreads();
    int d = t >> 1, sh = (t & 1) << 5;
    bf16* dst = Vt + (size_t)n * 1048576 + (size_t)d * 8192 + s0 + sh;
#pragma unroll
    for (int q = 0; q < 4; q++) {
        bf16x8 o;
#pragma unroll
        for (int e = 0; e < 8; e++) o[e] = lt[sh + q * 8 + e][d];
        *(bf16x8*)&dst[q * 8] = o;
    }
}

// ---------------- cache_k repack: [s][n][d] fp32 -> Kb[n][s][d] bf16 (s >= 1024) ----------------
__global__ __launch_bounds__(256) void k_repack_k(const float* __restrict__ cache_k, bf16* __restrict__ Kb) {
    int s = 1024 + blockIdx.x;
    int t = threadIdx.x;
    int e = t * 8;
    int n = e >> 7, d = e & 127;
    const float4* p = (const float4*)&cache_k[(size_t)s * 2048 + e];
    float4 a = p[0], b = p[1];
    bf16x8 v;
    v[0] = (bf16)a.x; v[1] = (bf16)a.y; v[2] = (bf16)a.z; v[3] = (bf16)a.w;
    v[4] = (bf16)b.x; v[5] = (bf16)b.y; v[6] = (bf16)b.z; v[7] = (bf16)b.w;
    *(bf16x8*)&Kb[(size_t)n * 1048576 + (size_t)s * 128 + d] = v;
}

// ---------------- flash attention: swapped 32x32 MFMA, in-register softmax ----------------
// grid (8 qblk, 16 h, 6 z); 4 waves x 32 q each; KV tile 64.
// Staging: reg-staged (global->reg->ds_write), T14 split: next-tile loads
// issued before compute so HBM latency hides under MFMA/softmax.
// Scores^T: lane holds col q = lane&31; rows k = (r&3)+8*(r>>2)+4*(lane>>5) per 32-k tile.
__global__ __launch_bounds__(256, 2) void k_flash(
    const bf16* __restrict__ Qb, const bf16* __restrict__ Kb, const bf16* __restrict__ Vt,
    float* __restrict__ Opart, float2* __restrict__ MLpart) {
    int h = blockIdx.y, z = blockIdx.z;
    int q0 = blockIdx.x * 128;
    int t = threadIdx.x;
    int lane = t & 63, wq = t >> 6;
    int l31 = lane & 31, hi = lane >> 5;
    __shared__ bf16 Kl[64 * 128];   // [k][d], 16B slots XOR-swizzled by row&7
    __shared__ bf16 Vl[128 * 64];   // [d][s], 16B slots XOR-swizzled by d&7
    const bf16* Kh = Kb + (size_t)h * 1048576;
    const bf16* Vh = Vt + (size_t)h * 1048576;
    int q = q0 + wq * 32 + l31;
    bf16x8 qf[8];
#pragma unroll
    for (int db = 0; db < 8; db++)
        qf[db] = *(const bf16x8*)&Qb[(size_t)h * 131072 + (size_t)q * 128 + db * 16 + hi * 8];
    f32x16 o[4] = {};
    float mm = -1e30f, ll = 0.f;
    // staging addressing: linear global, swizzled LDS write (per-lane ds_write scatter)
    int krow = t >> 4;                                        // 0..15 (+16j)
    int kcol = (t & 15) * 8;
    int kdst = krow * 128 + (((t & 15) ^ (krow & 7)) * 8);
    int vrow = t >> 3;                                        // 0..31 (+32j)
    int vcol = (t & 7) * 8;
    int vdst = vrow * 64 + (((t & 7) ^ (vrow & 7)) * 8);
    int swr = (l31 & 7) << 3;
    int it0 = (128 * z) / 6, it1 = (128 * (z + 1)) / 6;
    bf16x8 kst[4], vst[4];
    {
        int s0 = it0 * 64;
#pragma unroll
        for (int j = 0; j < 4; j++)
            kst[j] = *(const bf16x8*)&Kh[(size_t)(s0 + krow + 16 * j) * 128 + kcol];
#pragma unroll
        for (int j = 0; j < 4; j++)
            vst[j] = *(const bf16x8*)&Vh[(size_t)(vrow + 32 * j) * 8192 + s0 + vcol];
    }
    for (int it = it0; it < it1; ++it) {
        __syncthreads();   // previous iteration's LDS reads complete
#pragma unroll
        for (int j = 0; j < 4; j++) *(bf16x8*)&Kl[kdst + j * 2048] = kst[j];
#pragma unroll
        for (int j = 0; j < 4; j++) *(bf16x8*)&Vl[vdst + j * 2048] = vst[j];
        __syncthreads();   // LDS tile ready
        if (it + 1 < it1) {
            int s1 = (it + 1) * 64;
#pragma unroll
            for (int j = 0; j < 4; j++)
                kst[j] = *(const bf16x8*)&Kh[(size_t)(s1 + krow + 16 * j) * 128 + kcol];
#pragma unroll
            for (int j = 0; j < 4; j++)
                vst[j] = *(const bf16x8*)&Vh[(size_t)(vrow + 32 * j) * 8192 + s1 + vcol];
        }
        // QK^T swapped: sA = K[0:32] x Q^T, sB = K[32:64] x Q^T
        f32x16 sA = {}, sB = {};
#pragma unroll
        for (int db = 0; db < 8; db++) {
            int doff = (db * 16 + hi * 8) ^ swr;
            bf16x8 ka = *(const bf16x8*)&Kl[l31 * 128 + doff];
            bf16x8 kb = *(const bf16x8*)&Kl[(32 + l31) * 128 + doff];
            sA = MFMA32(ka, qf[db], sA);
            sB = MFMA32(kb, qf[db], sB);
        }
        // in-register softmax (base-2), defer-max
        float tm = -1e30f;
#pragma unroll
        for (int r = 0; r < 16; r++) { tm = fmaxf(tm, sA[r]); tm = fmaxf(tm, sB[r]); }
        tm = fmaxf(tm, __shfl_xor(tm, 32));
        if (__any(tm > mm + 11.5416f)) {
            float mn = fmaxf(mm, tm);
            float al = exp2f(mm - mn);
#pragma unroll
            for (int dt = 0; dt < 4; dt++)
#pragma unroll
                for (int r = 0; r < 16; r++) o[dt][r] *= al;
            ll *= al; mm = mn;
        }
        float ps = 0.f;
#pragma unroll
        for (int r = 0; r < 16; r++) { sA[r] = exp2f(sA[r] - mm); ps += sA[r]; }
#pragma unroll
        for (int r = 0; r < 16; r++) { sB[r] = exp2f(sB[r] - mm); ps += sB[r]; }
        ll += ps + __shfl_xor(ps, 32);
        // pack P to bf16 words: w[2*qd+j] = regs 4qd+2j, 4qd+2j+1
        unsigned int w0[8], w1[8];
#pragma unroll
        for (int qd = 0; qd < 4; qd++) {
            w0[qd * 2]     = pkbf(sA[qd * 4], sA[qd * 4 + 1]);
            w0[qd * 2 + 1] = pkbf(sA[qd * 4 + 2], sA[qd * 4 + 3]);
            w1[qd * 2]     = pkbf(sB[qd * 4], sB[qd * 4 + 1]);
            w1[qd * 2 + 1] = pkbf(sB[qd * 4 + 2], sB[qd * 4 + 3]);
        }
        // PV: O^T += V^T x P^T, 4 k-steps of 16
#pragma unroll
        for (int ks = 0; ks < 4; ks++) {
            const int a4 = (ks & 1) * 4;
            unsigned int oo0, oo1, ss0, ss1;
            if ((ks >> 1) == 0) {
                oo0 = hi ? w0[a4 + 2] : w0[a4];
                oo1 = hi ? w0[a4 + 3] : w0[a4 + 1];
                ss0 = hi ? w0[a4] : w0[a4 + 2];
                ss1 = hi ? w0[a4 + 1] : w0[a4 + 3];
            } else {
                oo0 = hi ? w1[a4 + 2] : w1[a4];
                oo1 = hi ? w1[a4 + 3] : w1[a4 + 1];
                ss0 = hi ? w1[a4] : w1[a4 + 2];
                ss1 = hi ? w1[a4 + 1] : w1[a4 + 3];
            }
            unsigned int x0 = (unsigned int)__shfl_xor((int)ss0, 32);
            unsigned int x1 = (unsigned int)__shfl_xor((int)ss1, 32);
            union { unsigned int w[4]; bf16x8 v; } fr;
            fr.w[0] = hi ? x0 : oo0;
            fr.w[1] = hi ? x1 : oo1;
            fr.w[2] = hi ? oo0 : x0;
            fr.w[3] = hi ? oo1 : x1;
#pragma unroll
            for (int dt = 0; dt < 4; dt++) {
                int e = (dt * 32 + l31) * 64 + ((ks * 16 + hi * 8) ^ swr);
                bf16x8 vf = *(const bf16x8*)&Vl[e];
                o[dt] = MFMA32(vf, fr.v, o[dt]);
            }
        }
    }
    size_t obase = ((size_t)(z * 16 + h) * 1024 + q) * 128;
#pragma unroll
    for (int dt = 0; dt < 4; dt++)
#pragma unroll
        for (int r = 0; r < 16; r++) {
            int d = dt * 32 + (r & 3) + 8 * (r >> 2) + 4 * hi;
            Opart[obase + d] = o[dt][r];
        }
    if (hi == 0) MLpart[(size_t)(z * 16 + h) * 1024 + q] = make_float2(mm, ll);
}

// ---------------- combine 6 partials -> Ob bf16 [q][h*128+d] ----------------
__global__ __launch_bounds__(256) void k_combine(
    const float* __restrict__ Opart, const float2* __restrict__ MLpart,
    bf16* __restrict__ Ob) {
    int q = blockIdx.x, t = threadIdx.x;
    int h = t >> 4, d0 = (t & 15) * 8;
    float m[6], l[6];
#pragma unroll
    for (int z = 0; z < 6; z++) {
        float2 v = MLpart[(size_t)(z * 16 + h) * 1024 + q];
        m[z] = v.x; l[z] = v.y;
    }
    float M = -1e30f;
#pragma unroll
    for (int z = 0; z < 6; z++) M = fmaxf(M, m[z]);
    float e[6], den = 0.f;
#pragma unroll
    for (int z = 0; z < 6; z++) { e[z] = exp2f(m[z] - M); den += e[z] * l[z]; }
    float inv = 1.0f / den;
    float acc[8] = {};
#pragma unroll
    for (int z = 0; z < 6; z++) {
        const float4* p = (const float4*)&Opart[((size_t)(z * 16 + h) * 1024 + q) * 128 + d0];
        float4 a = p[0], b = p[1];
        float s = e[z] * inv;
        acc[0] += a.x * s; acc[1] += a.y * s; acc[2] += a.z * s; acc[3] += a.w * s;
        acc[4] += b.x * s; acc[5] += b.y * s; acc[6] += b.z * s; acc[7] += b.w * s;
    }
    bf16x8 ov;
#pragma unroll
    for (int j = 0; j < 8; j++) ov[j] = (bf16)acc[j];
    *(bf16x8*)&Ob[(size_t)q * 2048 + h * 128 + d0] = ov;
}

extern "C" void kernel_launch(void* const* d_in, const int* in_sizes, int n_in,
                              void* d_out, int out_size, void* d_ws, size_t ws_size,
                              hipStream_t stream) {
    const float* x       = (const float*)d_in[0];
    const float* cache_k = (const float*)d_in[1];
    const float* cache_v = (const float*)d_in[2];
    const float* theta   = (const float*)d_in[5];
    const float* Wq = (const float*)d_in[6];
    const float* bq = (const float*)d_in[7];
    const float* Wk = (const float*)d_in[8];
    const float* bk = (const float*)d_in[9];
    const float* Wv = (const float*)d_in[10];
    const float* bv = (const float*)d_in[11];
    const float* Wo = (const float*)d_in[12];
    const float* bo = (const float*)d_in[13];
    const float* gq = (const float*)d_in[14];
    const float* gk = (const float*)d_in[15];
    float* out = (float*)d_out;

    // ws layout (132 MB). WoT placed before WqT so WqT..vraw (48MB) is a
    // contiguous dead region at flash time -> Opart overlay.
    bf16* xbf = (bf16*)d_ws;                 // 4 MB; dead after QKV gemm -> MLpart
    bf16* WoT = xbf + 2097152;               // 8 MB (alive until final gemm)
    bf16* WqT = WoT + 4194304;               // 8 MB
    bf16* WkT = WqT + 4194304;
    bf16* WvT = WkT + 4194304;
    float* qraw = (float*)(WvT + 4194304);   // 8 MB each
    float* kraw = qraw + 2097152;
    float* vraw = kraw + 2097152;
    bf16* Qb = (bf16*)(vraw + 2097152);      // [16][1024][128]
    bf16* Kb = Qb + 2097152;                 // [16][8192][128]
    bf16* Vt = Kb + 16777216;                // [16][128][8192]
    bf16* Ob = Vt + 16777216;                // [1024][2048]

    float* Opart = (float*)WqT;              // [6][16][1024][128] fp32 = 48 MB
    float2* MLpart = (float2*)xbf;           // [6][16][1024] float2 = 768 KB

    k_cvt_x<<<1024, 256, 0, stream>>>(x, xbf);
    k_wt<<<dim3(32, 32), 256, 0, stream>>>(Wq, WqT);
    k_wt<<<dim3(32, 32), 256, 0, stream>>>(Wk, WkT);
    k_wt<<<dim3(32, 32), 256, 0, stream>>>(Wv, WvT);
    k_wt<<<dim3(32, 32), 256, 0, stream>>>(Wo, WoT);
    k_gemm<<<dim3(16, 8, 3), 256, 0, stream>>>(xbf, WqT, WkT, WvT, bq, bk, bv, qraw, kraw, vraw);
    k_normrope<<<1024, 256, 0, stream>>>(qraw, kraw, gq, gk, theta, Qb, Kb);
    k_vtrans<<<dim3(128, 16), 256, 0, stream>>>(vraw, cache_v, Vt);
    k_repack_k<<<7168, 256, 0, stream>>>(cache_k, Kb);
    k_flash<<<dim3(8, 16, 6), 256, 0, stream>>>(Qb, Kb, Vt, Opart, MLpart);
    k_combine<<<1024, 256, 0, stream>>>(Opart, MLpart, Ob);
    k_gemm<<<dim3(16, 8, 1), 256, 0, stream>>>(Ob, WoT, WoT, WoT, bo, bo, bo, out, out, out);
}